// Round 2
// baseline (220.965 us; speedup 1.0000x reference)
//
#include <hip/hip_runtime.h>

typedef _Float16 half8 __attribute__((ext_vector_type(8)));
typedef float    f32x16 __attribute__((ext_vector_type(16)));

constexpr int kH = 16;    // heads
constexpr int kO = 1024;  // codebook options
constexpr int kA = 128;   // head size
constexpr int kBS = 4096; // B*S positions
constexpr int MTILE = 64; // positions per block
constexpr int NITER = 16; // (kO/2)/32 n-iterations per wave
constexpr int kWElems = kH * kO * kA; // 2,097,152

// ---- Pass 1: split W (fp32) into fp16 hi/lo planes in workspace ----
__global__ void split_w(const float* __restrict__ w,
                        _Float16* __restrict__ whi, _Float16* __restrict__ wlo) {
    int i = (blockIdx.x * 256 + threadIdx.x) * 4;
    float4 v = *(const float4*)(w + i);
    _Float16 h0 = (_Float16)v.x, h1 = (_Float16)v.y, h2 = (_Float16)v.z, h3 = (_Float16)v.w;
    _Float16 l0 = (_Float16)(v.x - (float)h0), l1 = (_Float16)(v.y - (float)h1);
    _Float16 l2 = (_Float16)(v.z - (float)h2), l3 = (_Float16)(v.w - (float)h3);
    ushort4 hv = { __builtin_bit_cast(ushort, h0), __builtin_bit_cast(ushort, h1),
                   __builtin_bit_cast(ushort, h2), __builtin_bit_cast(ushort, h3) };
    ushort4 lv = { __builtin_bit_cast(ushort, l0), __builtin_bit_cast(ushort, l1),
                   __builtin_bit_cast(ushort, l2), __builtin_bit_cast(ushort, l3) };
    *(ushort4*)((ushort*)whi + i) = hv;
    *(ushort4*)((ushort*)wlo + i) = lv;
}

// ---- Pass 2: fused logits (fp16-split MFMA, fp32 accum) + argmax + codebook gather ----
// Block: one head h, 64 positions. 4 waves: wave = (nhalf<<1)|mtile.
// Wave computes logits[32 pos][512 options] in 16 n-iters of 32x32 tiles:
//   acc += xh*wh + xh*wl + xl*wh  (K=128 = 8 mfma_32x32x16 steps per term)
__launch_bounds__(256, 2)
__global__ void vq_argmax_gather(const float* __restrict__ x,
                                 const _Float16* __restrict__ whi,
                                 const _Float16* __restrict__ wlo,
                                 const float* __restrict__ cb,
                                 float* __restrict__ out) {
    __shared__ float red_max[2][MTILE];
    __shared__ int   red_idx[2][MTILE];

    const int tid   = threadIdx.x;
    const int lane  = tid & 63;
    const int wv    = tid >> 6;
    const int nhalf = wv >> 1;
    const int mtile = wv & 1;
    const int h     = blockIdx.x & (kH - 1);
    const int p0    = (blockIdx.x >> 4) * MTILE;

    const int l31  = lane & 31;
    const int half = lane >> 5;

    // A fragments: split x row into fp16 hi/lo, registers only.
    // 32x32x16 A layout: m = lane&31, k = (lane>>5)*8 + j (verified-by-analogy w/ 16x16x32)
    const int mrow = p0 + mtile * 32 + l31;
    const float* xbase = x + (mrow * kH + h) * kA + half * 8;
    half8 ah[8], al[8];
#pragma unroll
    for (int ks = 0; ks < 8; ++ks) {
        float4 v0 = *(const float4*)(xbase + ks * 16);
        float4 v1 = *(const float4*)(xbase + ks * 16 + 4);
        float va[8] = { v0.x, v0.y, v0.z, v0.w, v1.x, v1.y, v1.z, v1.w };
        half8 hi, lo;
#pragma unroll
        for (int j = 0; j < 8; ++j) {
            _Float16 hj = (_Float16)va[j];
            hi[j] = hj;
            lo[j] = (_Float16)(va[j] - (float)hj);
        }
        ah[ks] = hi; al[ks] = lo;
    }

    const int nwb = nhalf * (kO / 2);
    const ushort* bh_base = (const ushort*)whi + (h * kO + nwb) * kA + half * 8;
    const ushort* bl_base = (const ushort*)wlo + (h * kO + nwb) * kA + half * 8;

    float best[16];
    int   bidx[16];
#pragma unroll
    for (int r = 0; r < 16; ++r) { best[r] = -1e30f; bidx[r] = 0; }

    for (int it = 0; it < NITER; ++it) {
        const int orow = it * 32 + l31;           // option row within this half
        const ushort* bhp = bh_base + orow * kA;
        const ushort* blp = bl_base + orow * kA;
        uint4 bh[8], bl[8];
#pragma unroll
        for (int ks = 0; ks < 8; ++ks) {
            bh[ks] = *(const uint4*)(bhp + ks * 16);
            bl[ks] = *(const uint4*)(blp + ks * 16);
        }
        f32x16 acc = {};
#pragma unroll
        for (int ks = 0; ks < 8; ++ks) {
            half8 bhk = __builtin_bit_cast(half8, bh[ks]);
            half8 blk = __builtin_bit_cast(half8, bl[ks]);
            acc = __builtin_amdgcn_mfma_f32_32x32x16_f16(ah[ks], bhk, acc, 0, 0, 0);
            acc = __builtin_amdgcn_mfma_f32_32x32x16_f16(ah[ks], blk, acc, 0, 0, 0);
            acc = __builtin_amdgcn_mfma_f32_32x32x16_f16(al[ks], bhk, acc, 0, 0, 0);
        }
        const int o = nwb + it * 32 + l31;        // column this lane owns
#pragma unroll
        for (int r = 0; r < 16; ++r) {
            if (acc[r] > best[r]) { best[r] = acc[r]; bidx[r] = o; } // strict >: first index on ties
        }
    }

    // reduce over the 32 columns (lanes of same half hold the same 16 rows)
#pragma unroll
    for (int s = 1; s < 32; s <<= 1) {
#pragma unroll
        for (int r = 0; r < 16; ++r) {
            float om = __shfl_xor(best[r], s, 64);
            int   oi = __shfl_xor(bidx[r], s, 64);
            if (om > best[r] || (om == best[r] && oi < bidx[r])) {
                best[r] = om; bidx[r] = oi;
            }
        }
    }
    if (l31 == 0) {
#pragma unroll
        for (int r = 0; r < 16; ++r) {
            int row = (r & 3) + 8 * (r >> 2) + 4 * half;  // C/D row mapping (m74/m101)
            red_max[nhalf][mtile * 32 + row] = best[r];
            red_idx[nhalf][mtile * 32 + row] = bidx[r];
        }
    }
    __syncthreads();

    // gather: out[p0+row, h, :] = cb[h, argmax, :]  (fp32, 32 lanes x float4 per row)
    for (int i = tid; i < MTILE * 32; i += 256) {
        int row = i >> 5, ch = i & 31;
        float m0 = red_max[0][row], m1 = red_max[1][row];
        int o = (m1 > m0) ? red_idx[1][row] : red_idx[0][row]; // ties -> half 0 (smaller o)
        float4 v = *(const float4*)(cb + (h * kO + o) * kA + ch * 4);
        *(float4*)(out + ((p0 + row) * kH + h) * kA + ch * 4) = v;
    }
}

extern "C" void kernel_launch(void* const* d_in, const int* in_sizes, int n_in,
                              void* d_out, int out_size, void* d_ws, size_t ws_size,
                              hipStream_t stream) {
    const float* x  = (const float*)d_in[0];   // [4096,16,128] fp32
    const float* w  = (const float*)d_in[1];   // [16,1024,128] fp32
    const float* cb = (const float*)d_in[2];   // [16,1024,128] fp32
    // d_in[3] = temperature: forward value is temperature-independent (softmax terms cancel)
    float* out = (float*)d_out;                // [4096,16,128] fp32

    _Float16* whi = (_Float16*)d_ws;                    // 4 MiB
    _Float16* wlo = (_Float16*)((char*)d_ws + (size_t)kWElems * 2); // 4 MiB

    split_w<<<dim3(kWElems / 4 / 256), dim3(256), 0, stream>>>(w, whi, wlo);
    vq_argmax_gather<<<dim3((kBS / MTILE) * kH), dim3(256), 0, stream>>>(x, whi, wlo, cb, out);
}

// Round 3
// 214.969 us; speedup vs baseline: 1.0279x; 1.0279x over previous
//
#include <hip/hip_runtime.h>

typedef _Float16 half8 __attribute__((ext_vector_type(8)));
typedef float    f32x16 __attribute__((ext_vector_type(16)));

constexpr int kH = 16;    // heads
constexpr int kO = 1024;  // codebook options
constexpr int kA = 128;   // head size
constexpr int kBS = 4096; // B*S positions
constexpr int MTILE = 64; // positions per block
constexpr int NITER = 16; // (kO/2)/32 option-tiles per wave
constexpr int kWElems = kH * kO * kA;

// ---- Pass 1: split W (fp32) into fp16 hi/lo planes in workspace ----
__global__ void split_w(const float* __restrict__ w,
                        _Float16* __restrict__ whi, _Float16* __restrict__ wlo) {
    int i = (blockIdx.x * 256 + threadIdx.x) * 4;
    float4 v = *(const float4*)(w + i);
    _Float16 h0 = (_Float16)v.x, h1 = (_Float16)v.y, h2 = (_Float16)v.z, h3 = (_Float16)v.w;
    _Float16 l0 = (_Float16)(v.x - (float)h0), l1 = (_Float16)(v.y - (float)h1);
    _Float16 l2 = (_Float16)(v.z - (float)h2), l3 = (_Float16)(v.w - (float)h3);
    ushort4 hv = { __builtin_bit_cast(ushort, h0), __builtin_bit_cast(ushort, h1),
                   __builtin_bit_cast(ushort, h2), __builtin_bit_cast(ushort, h3) };
    ushort4 lv = { __builtin_bit_cast(ushort, l0), __builtin_bit_cast(ushort, l1),
                   __builtin_bit_cast(ushort, l2), __builtin_bit_cast(ushort, l3) };
    *(ushort4*)((ushort*)whi + i) = hv;
    *(ushort4*)((ushort*)wlo + i) = lv;
}

// ---- Pass 2: fused logits + argmax + gather.
// A-operand = W option rows (streamed, double-buffered), B-operand = x position
// rows (stationary). acc: row=option, col=position -> per-iter fold to scalar.
__launch_bounds__(256, 2)
__global__ void vq_argmax_gather(const float* __restrict__ x,
                                 const _Float16* __restrict__ whi,
                                 const _Float16* __restrict__ wlo,
                                 const float* __restrict__ cb,
                                 float* __restrict__ out) {
    __shared__ float red_max[2][MTILE];
    __shared__ int   red_idx[2][MTILE];

    const int tid   = threadIdx.x;
    const int lane  = tid & 63;
    const int wv    = tid >> 6;
    const int nhalf = wv >> 1;       // option half
    const int mtile = wv & 1;        // position tile
    const int bid   = blockIdx.x;
    // XCD-aware: blocks on XCD x (bid%8) touch only heads {2x, 2x+1} -> W+cb L2-resident
    const int h  = ((bid & 7) << 1) | ((bid >> 3) & 1);
    const int p0 = (bid >> 4) * MTILE;

    const int l31  = lane & 31;
    const int half = lane >> 5;

    const int nwb = nhalf * (kO / 2);
    const ushort* bh_base = (const ushort*)whi + (h * kO + nwb) * kA + half * 8;
    const ushort* bl_base = (const ushort*)wlo + (h * kO + nwb) * kA + half * 8;

    uint4 wh0[8], wl0[8], wh1[8], wl1[8];
    auto loadW = [&](uint4* dh, uint4* dl, int it) {
        const ushort* hp = bh_base + (it * 32 + l31) * kA;
        const ushort* lp = bl_base + (it * 32 + l31) * kA;
#pragma unroll
        for (int ks = 0; ks < 8; ++ks) {
            dh[ks] = *(const uint4*)(hp + ks * 16);
            dl[ks] = *(const uint4*)(lp + ks * 16);
        }
    };

    loadW(wh0, wl0, 0);  // issue W tile 0 first; latency hidden under x load+convert

    // x stationary fragments (split fp32 -> fp16 hi/lo in-register)
    const int mrow = p0 + mtile * 32 + l31;
    const float* xbase = x + (mrow * kH + h) * kA + half * 8;
    half8 xh[8], xl[8];
#pragma unroll
    for (int ks = 0; ks < 8; ++ks) {
        float4 v0 = *(const float4*)(xbase + ks * 16);
        float4 v1 = *(const float4*)(xbase + ks * 16 + 4);
        float va[8] = { v0.x, v0.y, v0.z, v0.w, v1.x, v1.y, v1.z, v1.w };
        half8 hi, lo;
#pragma unroll
        for (int j = 0; j < 8; ++j) {
            _Float16 hj = (_Float16)va[j];
            hi[j] = hj;
            lo[j] = (_Float16)(va[j] - (float)hj);
        }
        xh[ks] = hi; xl[ks] = lo;
    }

    float best = -1e30f;
    int   bidx = 0;

    auto compute = [&](const uint4* dh, const uint4* dl, int it) {
        f32x16 a1 = {};  // wh * xh
        f32x16 a2 = {};  // wh * xl + wl * xh
#pragma unroll
        for (int ks = 0; ks < 8; ++ks) {
            half8 whk = __builtin_bit_cast(half8, dh[ks]);
            half8 wlk = __builtin_bit_cast(half8, dl[ks]);
            a1 = __builtin_amdgcn_mfma_f32_32x32x16_f16(whk, xh[ks], a1, 0, 0, 0);
            a2 = __builtin_amdgcn_mfma_f32_32x32x16_f16(whk, xl[ks], a2, 0, 0, 0);
            a2 = __builtin_amdgcn_mfma_f32_32x32x16_f16(wlk, xh[ks], a2, 0, 0, 0);
        }
        // fold 16 option-rows (this lane, position col = l31); rows ascend with r
        float lv = a1[0] + a2[0];
        int   lr = 0;
#pragma unroll
        for (int r = 1; r < 16; ++r) {
            float v = a1[r] + a2[r];
            if (v > lv) { lv = v; lr = r; }          // strict >: earliest row wins
        }
        int li = nwb + it * 32 + 4 * half + (lr & 3) + 8 * (lr >> 2);
        if (lv > best) { best = lv; bidx = li; }     // strict >: earlier iter wins
    };

    // software-pipelined option loop, register-double-buffered W tiles
    for (int it2 = 0; it2 < NITER; it2 += 2) {
        loadW(wh1, wl1, it2 + 1);
        compute(wh0, wl0, it2);
        if (it2 + 2 < NITER) loadW(wh0, wl0, it2 + 2);
        compute(wh1, wl1, it2 + 1);
    }

    // merge the two lane-halves (they hold disjoint option-row sets, same position)
    {
        float om = __shfl_xor(best, 32, 64);
        int   oi = __shfl_xor(bidx, 32, 64);
        if (om > best || (om == best && oi < bidx)) { best = om; bidx = oi; }
    }
    if (half == 0) {
        red_max[nhalf][mtile * 32 + l31] = best;
        red_idx[nhalf][mtile * 32 + l31] = bidx;
    }
    __syncthreads();

    // gather: out[p0+row, h, :] = cb[h, argmax, :]
    for (int i = tid; i < MTILE * 32; i += 256) {
        int row = i >> 5, ch = i & 31;
        float m0 = red_max[0][row], m1 = red_max[1][row];
        int o = (m1 > m0) ? red_idx[1][row] : red_idx[0][row]; // ties -> half 0 (smaller o)
        float4 v = *(const float4*)(cb + (h * kO + o) * kA + ch * 4);
        *(float4*)(out + ((p0 + row) * kH + h) * kA + ch * 4) = v;
    }
}

extern "C" void kernel_launch(void* const* d_in, const int* in_sizes, int n_in,
                              void* d_out, int out_size, void* d_ws, size_t ws_size,
                              hipStream_t stream) {
    const float* x  = (const float*)d_in[0];   // [4096,16,128] fp32
    const float* w  = (const float*)d_in[1];   // [16,1024,128] fp32
    const float* cb = (const float*)d_in[2];   // [16,1024,128] fp32
    // d_in[3] = temperature: forward value is temperature-independent
    float* out = (float*)d_out;                // [4096,16,128] fp32

    _Float16* whi = (_Float16*)d_ws;
    _Float16* wlo = (_Float16*)((char*)d_ws + (size_t)kWElems * 2);

    split_w<<<dim3(kWElems / 4 / 256), dim3(256), 0, stream>>>(w, whi, wlo);
    vq_argmax_gather<<<dim3((kBS / MTILE) * kH), dim3(256), 0, stream>>>(x, whi, wlo, cb, out);
}

// Round 5
// 153.201 us; speedup vs baseline: 1.4423x; 1.4032x over previous
//
#include <hip/hip_runtime.h>

typedef _Float16 half8 __attribute__((ext_vector_type(8)));
typedef float    f32x16 __attribute__((ext_vector_type(16)));

constexpr int kH = 16;    // heads
constexpr int kO = 1024;  // codebook options
constexpr int kA = 128;   // head size
constexpr int kBS = 4096; // B*S positions
constexpr int MTILE = 64; // positions per block
constexpr int NITER = 16; // option-tiles (32 options) per wave

// ---- Pass 1: split W into fp16 hi/lo planes, packed FRAGMENT-MAJOR ----
// Packed layout (halfs): [(h*32 + t)*2 + plane][ks][lane][8]
//   tile t = o>>5 (32 options), ks = a>>4, lane = (a>>3 & 1)*32 + (o&31), j = a&7
// so each (tile, ks, plane) is 64 lanes x 16 B contiguous -> coalesced loads.
__global__ void split_w(const float* __restrict__ w, ushort* __restrict__ wp) {
    int idx  = blockIdx.x * 256 + threadIdx.x;   // 2^18 threads x 8 elements
    int l31  = idx & 31;
    int half = (idx >> 5) & 1;
    int ks   = (idx >> 6) & 7;
    int t    = (idx >> 9) & 31;
    int h    = idx >> 14;
    const float* src = w + ((h * kO + t * 32 + l31) * kA) + ks * 16 + half * 8;
    float4 v0 = *(const float4*)(src);
    float4 v1 = *(const float4*)(src + 4);
    float va[8] = { v0.x, v0.y, v0.z, v0.w, v1.x, v1.y, v1.z, v1.w };
    ushort hh[8], ll[8];
#pragma unroll
    for (int j = 0; j < 8; ++j) {
        _Float16 hj = (_Float16)va[j];
        _Float16 lj = (_Float16)(va[j] - (float)hj);
        hh[j] = __builtin_bit_cast(ushort, hj);
        ll[j] = __builtin_bit_cast(ushort, lj);
    }
    ushort4 hv0 = { hh[0], hh[1], hh[2], hh[3] }, hv1 = { hh[4], hh[5], hh[6], hh[7] };
    ushort4 lv0 = { ll[0], ll[1], ll[2], ll[3] }, lv1 = { ll[4], ll[5], ll[6], ll[7] };
    int lane = half * 32 + l31;
    ushort* dhi = wp + (h * 32 + t) * 8192 + ks * 512 + lane * 8;  // plane 0 (hi)
    *(ushort4*)(dhi)        = hv0;
    *(ushort4*)(dhi + 4)    = hv1;
    *(ushort4*)(dhi + 4096) = lv0;   // plane 1 (lo)
    *(ushort4*)(dhi + 4100) = lv1;
}

// ---- Pass 2: fused logits (fp16-split, fp32 accum) + argmax + gather ----
// Block: head h, 64 positions; 4 waves = (nhalf<<1)|mtile. A=W rows, B=x cols.
// Single W reg buffer sequenced hi->lo to stay under 128 VGPRs (4 waves/SIMD).
__launch_bounds__(256, 4)
__global__ void vq_argmax_gather(const float* __restrict__ x,
                                 const ushort* __restrict__ wp,
                                 const float* __restrict__ cb,
                                 float* __restrict__ out) {
    __shared__ float red_max[2][MTILE];
    __shared__ int   red_idx[2][MTILE];

    const int tid   = threadIdx.x;
    const int lane  = tid & 63;
    const int wv    = tid >> 6;
    const int nhalf = wv >> 1;
    const int mtile = wv & 1;
    const int bid   = blockIdx.x;
    // XCD-aware: XCD (bid&7) touches only heads {2x,2x+1} -> W+cb L2-resident
    const int h  = ((bid & 7) << 1) | ((bid >> 3) & 1);
    const int p0 = (bid >> 4) * MTILE;

    const int l31  = lane & 31;
    const int half = lane >> 5;

    // per-wave packed-W base: tiles t = nhalf*16 + it, stride 8192 halfs/tile
    const ushort* wbase = wp + (h * 32 + nhalf * 16) * 8192 + lane * 8;

    uint4 wreg[8];
    auto loadW = [&](int it, int plane) {
        const ushort* p = wbase + it * 8192 + plane * 4096;
#pragma unroll
        for (int ks = 0; ks < 8; ++ks)
            wreg[ks] = *(const uint4*)(p + ks * 512);   // 64 lanes x 16B contiguous
    };

    loadW(0, 0);  // prefetch tile 0 hi under the x load/convert phase

    // stationary x fragments (fp32 -> fp16 hi/lo in-register)
    const int mrow = p0 + mtile * 32 + l31;
    const float* xbase = x + (mrow * kH + h) * kA + half * 8;
    half8 xh[8], xl[8];
#pragma unroll
    for (int ks = 0; ks < 8; ++ks) {
        float4 v0 = *(const float4*)(xbase + ks * 16);
        float4 v1 = *(const float4*)(xbase + ks * 16 + 4);
        float va[8] = { v0.x, v0.y, v0.z, v0.w, v1.x, v1.y, v1.z, v1.w };
        half8 hi, lo;
#pragma unroll
        for (int j = 0; j < 8; ++j) {
            _Float16 hj = (_Float16)va[j];
            hi[j] = hj;
            lo[j] = (_Float16)(va[j] - (float)hj);
        }
        xh[ks] = hi; xl[ks] = lo;
    }

    float best = -1e30f;
    int   bidx = 0;
    const int nwb = nhalf * (kO / 2);

    for (int it = 0; it < NITER; ++it) {
        f32x16 acc = {};
        // phase 1+2: hi plane (already loaded) x {xh, xl}
#pragma unroll
        for (int ks = 0; ks < 8; ++ks)
            acc = __builtin_amdgcn_mfma_f32_32x32x16_f16(
                __builtin_bit_cast(half8, wreg[ks]), xh[ks], acc, 0, 0, 0);
#pragma unroll
        for (int ks = 0; ks < 8; ++ks)
            acc = __builtin_amdgcn_mfma_f32_32x32x16_f16(
                __builtin_bit_cast(half8, wreg[ks]), xl[ks], acc, 0, 0, 0);
        // phase 3: lo plane x xh (loads overlap the 16 MFMAs above via WAR reuse)
        loadW(it, 1);
#pragma unroll
        for (int ks = 0; ks < 8; ++ks)
            acc = __builtin_amdgcn_mfma_f32_32x32x16_f16(
                __builtin_bit_cast(half8, wreg[ks]), xh[ks], acc, 0, 0, 0);
        if (it + 1 < NITER) loadW(it + 1, 0);  // next tile hi

        // fold 16 option-rows into running scalar argmax (rows ascend with r)
        float lv = acc[0];
        int   lr = 0;
#pragma unroll
        for (int r = 1; r < 16; ++r) {
            if (acc[r] > lv) { lv = acc[r]; lr = r; }   // strict >: earliest row wins
        }
        int li = nwb + it * 32 + 4 * half + (lr & 3) + 8 * (lr >> 2);
        if (lv > best) { best = lv; bidx = li; }        // strict >: earlier tile wins
    }

    // merge lane halves (disjoint option rows, same position column)
    {
        float om = __shfl_xor(best, 32, 64);
        int   oi = __shfl_xor(bidx, 32, 64);
        if (om > best || (om == best && oi < bidx)) { best = om; bidx = oi; }
    }
    if (half == 0) {
        red_max[nhalf][mtile * 32 + l31] = best;
        red_idx[nhalf][mtile * 32 + l31] = bidx;
    }
    __syncthreads();

    // gather: out[p0+row, h, :] = cb[h, argmax, :]
    for (int i = tid; i < MTILE * 32; i += 256) {
        int row = i >> 5, ch = i & 31;
        float m0 = red_max[0][row], m1 = red_max[1][row];
        int o = (m1 > m0) ? red_idx[1][row] : red_idx[0][row]; // ties -> smaller o
        float4 v = *(const float4*)(cb + (h * kO + o) * kA + ch * 4);
        *(float4*)(out + ((p0 + row) * kH + h) * kA + ch * 4) = v;
    }
}

extern "C" void kernel_launch(void* const* d_in, const int* in_sizes, int n_in,
                              void* d_out, int out_size, void* d_ws, size_t ws_size,
                              hipStream_t stream) {
    const float* x  = (const float*)d_in[0];   // [4096,16,128] fp32
    const float* w  = (const float*)d_in[1];   // [16,1024,128] fp32
    const float* cb = (const float*)d_in[2];   // [16,1024,128] fp32
    // d_in[3] = temperature: forward value is temperature-independent
    float* out = (float*)d_out;                // [4096,16,128] fp32

    ushort* wpacked = (ushort*)d_ws;           // 8 MiB packed hi+lo planes

    split_w<<<dim3(1024), dim3(256), 0, stream>>>(w, wpacked);
    vq_argmax_gather<<<dim3((kBS / MTILE) * kH), dim3(256), 0, stream>>>(x, wpacked, cb, out);
}